// Round 10
// baseline (67.806 us; speedup 1.0000x reference)
//
#include <hip/hip_runtime.h>

using u16 = unsigned short;
using u32 = unsigned int;

#define ALPHA 0.2f
#define LOG2E 1.4426950408889634f

typedef __bf16 bf16x8 __attribute__((ext_vector_type(8)));
typedef float f32x4 __attribute__((ext_vector_type(4)));
typedef float f32x16 __attribute__((ext_vector_type(16)));

__device__ __forceinline__ u16 f2bf(float f) {
  u32 u = __builtin_bit_cast(u32, f);
  u += 0x7FFFu + ((u >> 16) & 1u);   // RTNE
  return (u16)(u >> 16);
}
__device__ __forceinline__ float bf2f(u16 h) {
  u32 u = ((u32)h) << 16;
  return __builtin_bit_cast(float, u);
}
__device__ __forceinline__ void gload_lds16(const void* g, void* l) {
  __builtin_amdgcn_global_load_lds((__attribute__((address_space(1))) void*)g,
                                   (__attribute__((address_space(3))) void*)l,
                                   16, 0, 0);
}

// ---------- cast+transpose W: wbt[n][k] = bf16(W[k][n]) ----------
__global__ __launch_bounds__(256) void k_cast_wT(const float* __restrict__ W, u16* __restrict__ wbt) {
  int idx = blockIdx.x * 256 + threadIdx.x;
  int k = idx >> 9, n = idx & 511;
  wbt[n * 512 + k] = f2bf(W[idx]);
}

// hbt2 tiled layout (u16 elems, per batch 512K):
//   IDX(m,f) = (m>>4)*8192 + (f>>5)*512 + ((m>>3)&1)*256 + (f&31)*8 + (m&7)

// ---------- gemm1: h = x@W (M=16384,K=512,N=512). 128x128 tile, 4 waves.
// Triple-buffered, counted vmcnt. XCD-swizzled. Epilogue: hbf + hbt2 + score partials.
__global__ __launch_bounds__(256, 2) void k_gemm1(const float* __restrict__ x, const u16* __restrict__ wbt,
                                                  const float* __restrict__ a,
                                                  u16* __restrict__ hbf, u16* __restrict__ hbt2,
                                                  float* __restrict__ s1p, float* __restrict__ s2p) {
  __shared__ __attribute__((aligned(16))) char lds[73728];
  __shared__ __attribute__((aligned(16))) float a_l[256];

  const int t = threadIdx.x;
  const int lane = t & 63;
  const int w = t >> 6;
  const int l31 = lane & 31, lhi = lane >> 5;
  const int rb = w >> 1, cg = w & 1;
  const int g = blockIdx.x;
  const int cb = (g >> 3) & 3;
  const int tile_m = (g & 7) | ((g >> 5) << 3);
  const int row0 = tile_m * 128;
  const int col0 = cb * 128;

  a_l[t] = (t < 128) ? a[col0 + t] : a[512 + col0 + (t - 128)];

  f32x16 acc[2][2];
#pragma unroll
  for (int i = 0; i < 2; ++i)
#pragma unroll
    for (int j = 0; j < 2; ++j)
#pragma unroll
      for (int r = 0; r < 16; ++r) acc[i][j][r] = 0.f;

#define STAGE_G1(kt, Ab, Bb)                                                              \
  {                                                                                       \
    const int k0_ = (kt) * 32;                                                            \
    _Pragma("unroll")                                                                     \
    for (int i = 0; i < 4; ++i) {                                                         \
      int G = i * 256 + t;                                                                \
      int row = G >> 3, ks = G & 7;                                                       \
      gload_lds16(x + (size_t)(row0 + row) * 512 + k0_ + ((ks ^ (row & 7)) * 4),          \
                  (Ab) + (size_t)(i * 256 + w * 64) * 16);                                \
    }                                                                                     \
    _Pragma("unroll")                                                                     \
    for (int i = 0; i < 2; ++i) {                                                         \
      int G = i * 256 + t;                                                                \
      int col = G >> 2, ks = G & 3;                                                       \
      gload_lds16(wbt + (size_t)(col0 + col) * 512 + k0_ + ((ks ^ ((col >> 1) & 3)) * 8), \
                  (Bb) + (size_t)(i * 256 + w * 64) * 16);                                \
    }                                                                                     \
  }

#define COMPUTE_G1(Ab, Bb)                                                                         \
  {                                                                                                \
    _Pragma("unroll")                                                                              \
    for (int ks = 0; ks < 2; ++ks) {                                                               \
      bf16x8 af[2];                                                                                \
      _Pragma("unroll")                                                                            \
      for (int sub = 0; sub < 2; ++sub) {                                                          \
        const int arow = rb * 64 + sub * 32 + l31;                                                 \
        const int kg = ks * 4 + lhi * 2;                                                           \
        f32x4 fa0 = *reinterpret_cast<const f32x4*>((Ab) + (size_t)(arow * 8 + (kg ^ (arow & 7))) * 16); \
        f32x4 fa1 = *reinterpret_cast<const f32x4*>((Ab) + (size_t)(arow * 8 + ((kg + 1) ^ (arow & 7))) * 16); \
        _Pragma("unroll")                                                                          \
        for (int jj = 0; jj < 4; ++jj) {                                                           \
          af[sub][jj] = (__bf16)fa0[jj];                                                           \
          af[sub][jj + 4] = (__bf16)fa1[jj];                                                       \
        }                                                                                          \
      }                                                                                            \
      bf16x8 bfr[2];                                                                               \
      _Pragma("unroll")                                                                            \
      for (int bt = 0; bt < 2; ++bt) {                                                             \
        const int bcol = cg * 64 + bt * 32 + l31;                                                  \
        const int kslot = (ks * 2 + lhi) ^ ((bcol >> 1) & 3);                                      \
        bfr[bt] = *reinterpret_cast<const bf16x8*>((Bb) + (size_t)(bcol * 4 + kslot) * 16);        \
      }                                                                                            \
      _Pragma("unroll")                                                                            \
      for (int sub = 0; sub < 2; ++sub)                                                            \
        _Pragma("unroll")                                                                          \
        for (int bt = 0; bt < 2; ++bt)                                                             \
          acc[sub][bt] = __builtin_amdgcn_mfma_f32_32x32x16_bf16(af[sub], bfr[bt], acc[sub][bt], 0, 0, 0); \
    }                                                                                              \
  }

  char* Ac = lds;             char* Bc = lds + 49152;
  char* An = lds + 16384;     char* Bn = lds + 57344;
  char* As = lds + 32768;     char* Bs = lds + 65536;

  STAGE_G1(0, Ac, Bc);
  STAGE_G1(1, An, Bn);
  __builtin_amdgcn_sched_barrier(0);
  asm volatile("s_waitcnt vmcnt(6) lgkmcnt(0)" ::: "memory");
  __builtin_amdgcn_s_barrier();
  __builtin_amdgcn_sched_barrier(0);

#pragma unroll 1
  for (int kt = 0; kt < 14; ++kt) {
    STAGE_G1(kt + 2, As, Bs);
    COMPUTE_G1(Ac, Bc);
    __builtin_amdgcn_sched_barrier(0);
    asm volatile("s_waitcnt vmcnt(6)" ::: "memory");
    __builtin_amdgcn_s_barrier();
    __builtin_amdgcn_sched_barrier(0);
    char* ta = Ac; Ac = An; An = As; As = ta;
    char* tb = Bc; Bc = Bn; Bn = Bs; Bs = tb;
  }
  COMPUTE_G1(Ac, Bc);
  __builtin_amdgcn_sched_barrier(0);
  asm volatile("s_waitcnt vmcnt(0)" ::: "memory");
  __builtin_amdgcn_s_barrier();
  __builtin_amdgcn_sched_barrier(0);
  COMPUTE_G1(An, Bn);
#undef STAGE_G1
#undef COMPUTE_G1

  __syncthreads();

  u16* lT = (u16*)lds;
#pragma unroll
  for (int sub = 0; sub < 2; ++sub)
#pragma unroll
    for (int bt = 0; bt < 2; ++bt) {
      const int col = cg * 64 + bt * 32 + l31;
#pragma unroll
      for (int r = 0; r < 16; ++r) {
        int row = rb * 64 + sub * 32 + (r & 3) + 8 * (r >> 2) + 4 * lhi;
        lT[row * 136 + col] = f2bf(acc[sub][bt][r]);
      }
    }
  __syncthreads();

#pragma unroll
  for (int i = 0; i < 8; ++i) {
    int G = i * 256 + t;
    int row = G >> 4, gg = G & 15;
    uint4 v = *reinterpret_cast<const uint4*>(&lT[row * 136 + gg * 8]);
    *reinterpret_cast<uint4*>(&hbf[(size_t)(row0 + row) * 512 + col0 + gg * 8]) = v;
  }
  const int bb = row0 >> 10;
  const int nb = row0 & 1023;
  u16* hb2 = hbt2 + (size_t)bb * 524288;
#pragma unroll
  for (int i = 0; i < 8; ++i) {
    int G = i * 256 + t;
    int col = G & 127, rg = G >> 7;
    u32 wd[4];
#pragma unroll
    for (int jj = 0; jj < 4; ++jj) {
      u16 lo = lT[(rg * 8 + 2 * jj) * 136 + col];
      u16 hi = lT[(rg * 8 + 2 * jj + 1) * 136 + col];
      wd[jj] = (u32)lo | ((u32)hi << 16);
    }
    uint4 o = {wd[0], wd[1], wd[2], wd[3]};
    const int m0 = nb + rg * 8;
    const int f = col0 + col;
    size_t idx = (size_t)(m0 >> 4) * 8192 + (size_t)(f >> 5) * 512 + (size_t)((m0 >> 3) & 1) * 256 + (size_t)(f & 31) * 8;
    *reinterpret_cast<uint4*>(&hb2[idx]) = o;
  }
  {
    const int r2 = t >> 1, half = t & 1;
    float d1 = 0.f, d2 = 0.f;
#pragma unroll
    for (int i = 0; i < 8; ++i) {
      uint4 v = *reinterpret_cast<const uint4*>(&lT[r2 * 136 + half * 64 + i * 8]);
      u32 wds[4] = {v.x, v.y, v.z, v.w};
#pragma unroll
      for (int jj = 0; jj < 8; ++jj) {
        float h = bf2f((u16)(wds[jj >> 1] >> ((jj & 1) * 16)));
        d1 += h * a_l[half * 64 + i * 8 + jj];
        d2 += h * a_l[128 + half * 64 + i * 8 + jj];
      }
    }
    d1 += __shfl_xor(d1, 1);
    d2 += __shfl_xor(d2, 1);
    if (half == 0) {
      s1p[cb * 16384 + row0 + r2] = d1;
      s2p[cb * 16384 + row0 + r2] = d2;
    }
  }
}

// ---------- reduce score partials -> s1L, s2L (scaled by log2e) ----------
__global__ __launch_bounds__(256) void k_reduce(const float* __restrict__ s1p, const float* __restrict__ s2p,
                                                float* __restrict__ s1L, float* __restrict__ s2L) {
  int id = blockIdx.x * 256 + threadIdx.x;
  float d1 = s1p[id] + s1p[16384 + id] + s1p[32768 + id] + s1p[49152 + id];
  float d2 = s2p[id] + s2p[16384 + id] + s2p[32768 + id] + s2p[49152 + id];
  s1L[id] = d1 * LOG2E;
  s2L[id] = d2 * LOG2E;
}

// ---------- attn: 16x16x32 MFMA, wave = 16 rows x 128 cols, 32 steps of 32 m.
// Grid 1024 (4 waves/SIMD capacity), depth-3 register pipeline, ones-MFMA denom. ----------
__global__ __launch_bounds__(256, 3) void k_attn(const u16* __restrict__ hbt2, const u16* __restrict__ hbf,
                                                 const float* __restrict__ s1Lg, const float* __restrict__ s2Lg,
                                                 const float* __restrict__ betag, float* __restrict__ out) {
  __shared__ __attribute__((aligned(16))) float e1_l[1024];
  __shared__ __attribute__((aligned(16))) float e2_l[1024];
  const int t = threadIdx.x;
  const int lane = t & 63;
  const int w = t >> 6;
  const int fl = lane & 15;          // A-row / B-col lane part
  const int mg = lane >> 4;          // m-slice group (0..3)

  const int B = blockIdx.x;
  const int b = (B & 7) * 2 + ((B >> 3) & 1);   // XCD swizzle: 2 batches/XCD L2
  const int j = B >> 4;                          // 0..63 = 16 n-tiles x 4 c-tiles
  const int n0 = (j >> 2) * 64;
  const int c0 = (j & 3) * 128;

  const u16* hb2 = hbt2 + (size_t)b * 524288;

  for (int i = t; i < 1024; i += 256) {
    float v = s2Lg[b * 1024 + i];
    e1_l[i] = exp2f(v);
    e2_l[i] = exp2f(ALPHA * v);
  }

  const int myrow = n0 + w * 16 + fl;
  const float s1v = s1Lg[b * 1024 + myrow];
  const float c1 = exp2f(s1v), c2 = exp2f(ALPHA * s1v);

  f32x4 acc[8];
#pragma unroll
  for (int ct = 0; ct < 8; ++ct) acc[ct] = (f32x4){0.f, 0.f, 0.f, 0.f};
  f32x4 accs = (f32x4){0.f, 0.f, 0.f, 0.f};
  bf16x8 ones;
#pragma unroll
  for (int q = 0; q < 8; ++q) ones[q] = (__bf16)1.0f;

  __syncthreads();   // tables visible

  // per-lane base: col part fl*8, m-group part (mg>>1)*8192 + (mg&1)*256
  const u16* bp = hb2 + (size_t)(c0 >> 5) * 512 + (size_t)(mg >> 1) * 8192 + (size_t)(mg & 1) * 256 + (size_t)fl * 8;
  const int mgo = mg * 8;

#define LOAD_B(dst, s)                                                                          \
  {                                                                                             \
    const u16* np_ = bp + (size_t)(s) * 16384;                                                  \
    _Pragma("unroll")                                                                           \
    for (int ct = 0; ct < 8; ++ct)                                                              \
      dst[ct] = *reinterpret_cast<const bf16x8*>(np_ + (ct >> 1) * 512 + (ct & 1) * 128);       \
  }

#define STEP_ATTN(s, buf)                                                       \
  {                                                                             \
    const int mo = (s) * 32 + mgo;                                              \
    f32x4 ea = *reinterpret_cast<const f32x4*>(&e1_l[mo]);                      \
    f32x4 eb = *reinterpret_cast<const f32x4*>(&e1_l[mo + 4]);                  \
    f32x4 fa = *reinterpret_cast<const f32x4*>(&e2_l[mo]);                      \
    f32x4 fb = *reinterpret_cast<const f32x4*>(&e2_l[mo + 4]);                  \
    bf16x8 af;                                                                  \
    _Pragma("unroll")                                                           \
    for (int q = 0; q < 4; ++q) {                                               \
      af[q] = (__bf16)fmaxf(c1 * ea[q], c2 * fa[q]);                            \
      af[q + 4] = (__bf16)fmaxf(c1 * eb[q], c2 * fb[q]);                        \
    }                                                                           \
    accs = __builtin_amdgcn_mfma_f32_16x16x32_bf16(af, ones, accs, 0, 0, 0);    \
    _Pragma("unroll")                                                           \
    for (int ct = 0; ct < 8; ++ct)                                              \
      acc[ct] = __builtin_amdgcn_mfma_f32_16x16x32_bf16(af, (buf)[ct], acc[ct], 0, 0, 0); \
  }

  bf16x8 P0[8], P1[8], P2[8];
  LOAD_B(P0, 0);
  LOAD_B(P1, 1);
  LOAD_B(P2, 2);

#pragma unroll 1
  for (int s = 0; s < 30; s += 3) {
    STEP_ATTN(s + 0, P0); LOAD_B(P0, (s + 3) & 31);
    STEP_ATTN(s + 1, P1); LOAD_B(P1, (s + 4) & 31);
    STEP_ATTN(s + 2, P2); LOAD_B(P2, (s + 5) & 31);
  }
  STEP_ATTN(30, P0);
  STEP_ATTN(31, P1);
#undef LOAD_B
#undef STEP_ATTN

  const float beta = betag[0];
  const u16* hf = hbf + (size_t)b * 1024 * 512;
  f32x4 iv;
#pragma unroll
  for (int q = 0; q < 4; ++q) iv[q] = 1.0f / accs[q];
  const int rowb = n0 + w * 16 + (lane >> 4) * 4;   // C-layout rows
#pragma unroll
  for (int ct = 0; ct < 8; ++ct) {
    const int colv = c0 + ct * 16 + fl;
#pragma unroll
    for (int q = 0; q < 4; ++q) {
      float hv = bf2f(hf[(size_t)(rowb + q) * 512 + colv]);
      float xv = acc[ct][q] * iv[q] + beta * hv;
      out[((size_t)b * 1024 + rowb + q) * 512 + colv] = xv > 0.f ? xv : __expf(xv) - 1.0f;
    }
  }
}

extern "C" void kernel_launch(void* const* d_in, const int* in_sizes, int n_in,
                              void* d_out, int out_size, void* d_ws, size_t ws_size,
                              hipStream_t stream) {
  const float* x = (const float*)d_in[0];
  const float* W = (const float*)d_in[1];
  const float* a = (const float*)d_in[2];
  const float* beta = (const float*)d_in[3];
  float* out = (float*)d_out;

  char* ws = (char*)d_ws;
  u16* hbf = (u16*)ws;                              // 16 MB
  u16* hbt2 = (u16*)(ws + (16u << 20));             // 16 MB, tiled layout
  u16* wbt = (u16*)(ws + (32u << 20));              // 512 KB
  float* s1p = (float*)(ws + (32u << 20) + (512u << 10));   // 256 KB
  float* s2p = (float*)(ws + (32u << 20) + (768u << 10));   // 256 KB
  float* s1L = (float*)(ws + (33u << 20));          // 64 KB
  float* s2L = (float*)(ws + (33u << 20) + (64u << 10));

  k_cast_wT<<<1024, 256, 0, stream>>>(W, wbt);
  k_gemm1<<<512, 256, 0, stream>>>(x, wbt, a, hbf, hbt2, s1p, s2p);
  k_reduce<<<64, 256, 0, stream>>>(s1p, s2p, s1L, s2L);
  k_attn<<<1024, 256, 0, stream>>>(hbt2, hbf, s1L, s2L, beta, out);
}

// Round 11
// 62.461 us; speedup vs baseline: 1.0856x; 1.0856x over previous
//
#include <hip/hip_runtime.h>

using u16 = unsigned short;
using u32 = unsigned int;

#define ALPHA 0.2f
#define LOG2E 1.4426950408889634f

typedef __bf16 bf16x8 __attribute__((ext_vector_type(8)));
typedef float f32x4 __attribute__((ext_vector_type(4)));
typedef float f32x16 __attribute__((ext_vector_type(16)));

__device__ __forceinline__ u16 f2bf(float f) {
  u32 u = __builtin_bit_cast(u32, f);
  u += 0x7FFFu + ((u >> 16) & 1u);   // RTNE
  return (u16)(u >> 16);
}
__device__ __forceinline__ float bf2f(u16 h) {
  u32 u = ((u32)h) << 16;
  return __builtin_bit_cast(float, u);
}
__device__ __forceinline__ void gload_lds16(const void* g, void* l) {
  __builtin_amdgcn_global_load_lds((__attribute__((address_space(1))) void*)g,
                                   (__attribute__((address_space(3))) void*)l,
                                   16, 0, 0);
}

// ---------- cast+transpose W: wbt[n][k] = bf16(W[k][n]) ----------
__global__ __launch_bounds__(256) void k_cast_wT(const float* __restrict__ W, u16* __restrict__ wbt) {
  int idx = blockIdx.x * 256 + threadIdx.x;
  int k = idx >> 9, n = idx & 511;
  wbt[n * 512 + k] = f2bf(W[idx]);
}

// hbt2 tiled layout (u16 elems, per batch 512K):
//   IDX(m,f) = (m>>4)*8192 + (f>>5)*512 + ((m>>3)&1)*256 + (f&31)*8 + (m&7)

// ---------- gemm1: h = x@W (M=16384,K=512,N=512). 128x128 tile, 4 waves.
// Triple-buffered, counted vmcnt. XCD-swizzled. Epilogue: hbf + hbt2 + score partials.
__global__ __launch_bounds__(256, 2) void k_gemm1(const float* __restrict__ x, const u16* __restrict__ wbt,
                                                  const float* __restrict__ a,
                                                  u16* __restrict__ hbf, u16* __restrict__ hbt2,
                                                  float* __restrict__ s1p, float* __restrict__ s2p) {
  __shared__ __attribute__((aligned(16))) char lds[73728];
  __shared__ __attribute__((aligned(16))) float a_l[256];

  const int t = threadIdx.x;
  const int lane = t & 63;
  const int w = t >> 6;
  const int l31 = lane & 31, lhi = lane >> 5;
  const int rb = w >> 1, cg = w & 1;
  const int g = blockIdx.x;
  const int cb = (g >> 3) & 3;
  const int tile_m = (g & 7) | ((g >> 5) << 3);
  const int row0 = tile_m * 128;
  const int col0 = cb * 128;

  a_l[t] = (t < 128) ? a[col0 + t] : a[512 + col0 + (t - 128)];

  f32x16 acc[2][2];
#pragma unroll
  for (int i = 0; i < 2; ++i)
#pragma unroll
    for (int j = 0; j < 2; ++j)
#pragma unroll
      for (int r = 0; r < 16; ++r) acc[i][j][r] = 0.f;

#define STAGE_G1(kt, Ab, Bb)                                                              \
  {                                                                                       \
    const int k0_ = (kt) * 32;                                                            \
    _Pragma("unroll")                                                                     \
    for (int i = 0; i < 4; ++i) {                                                         \
      int G = i * 256 + t;                                                                \
      int row = G >> 3, ks = G & 7;                                                       \
      gload_lds16(x + (size_t)(row0 + row) * 512 + k0_ + ((ks ^ (row & 7)) * 4),          \
                  (Ab) + (size_t)(i * 256 + w * 64) * 16);                                \
    }                                                                                     \
    _Pragma("unroll")                                                                     \
    for (int i = 0; i < 2; ++i) {                                                         \
      int G = i * 256 + t;                                                                \
      int col = G >> 2, ks = G & 3;                                                       \
      gload_lds16(wbt + (size_t)(col0 + col) * 512 + k0_ + ((ks ^ ((col >> 1) & 3)) * 8), \
                  (Bb) + (size_t)(i * 256 + w * 64) * 16);                                \
    }                                                                                     \
  }

#define COMPUTE_G1(Ab, Bb)                                                                         \
  {                                                                                                \
    _Pragma("unroll")                                                                              \
    for (int ks = 0; ks < 2; ++ks) {                                                               \
      bf16x8 af[2];                                                                                \
      _Pragma("unroll")                                                                            \
      for (int sub = 0; sub < 2; ++sub) {                                                          \
        const int arow = rb * 64 + sub * 32 + l31;                                                 \
        const int kg = ks * 4 + lhi * 2;                                                           \
        f32x4 fa0 = *reinterpret_cast<const f32x4*>((Ab) + (size_t)(arow * 8 + (kg ^ (arow & 7))) * 16); \
        f32x4 fa1 = *reinterpret_cast<const f32x4*>((Ab) + (size_t)(arow * 8 + ((kg + 1) ^ (arow & 7))) * 16); \
        _Pragma("unroll")                                                                          \
        for (int jj = 0; jj < 4; ++jj) {                                                           \
          af[sub][jj] = (__bf16)fa0[jj];                                                           \
          af[sub][jj + 4] = (__bf16)fa1[jj];                                                       \
        }                                                                                          \
      }                                                                                            \
      bf16x8 bfr[2];                                                                               \
      _Pragma("unroll")                                                                            \
      for (int bt = 0; bt < 2; ++bt) {                                                             \
        const int bcol = cg * 64 + bt * 32 + l31;                                                  \
        const int kslot = (ks * 2 + lhi) ^ ((bcol >> 1) & 3);                                      \
        bfr[bt] = *reinterpret_cast<const bf16x8*>((Bb) + (size_t)(bcol * 4 + kslot) * 16);        \
      }                                                                                            \
      _Pragma("unroll")                                                                            \
      for (int sub = 0; sub < 2; ++sub)                                                            \
        _Pragma("unroll")                                                                          \
        for (int bt = 0; bt < 2; ++bt)                                                             \
          acc[sub][bt] = __builtin_amdgcn_mfma_f32_32x32x16_bf16(af[sub], bfr[bt], acc[sub][bt], 0, 0, 0); \
    }                                                                                              \
  }

  char* Ac = lds;             char* Bc = lds + 49152;
  char* An = lds + 16384;     char* Bn = lds + 57344;
  char* As = lds + 32768;     char* Bs = lds + 65536;

  STAGE_G1(0, Ac, Bc);
  STAGE_G1(1, An, Bn);
  __builtin_amdgcn_sched_barrier(0);
  asm volatile("s_waitcnt vmcnt(6) lgkmcnt(0)" ::: "memory");
  __builtin_amdgcn_s_barrier();
  __builtin_amdgcn_sched_barrier(0);

#pragma unroll 1
  for (int kt = 0; kt < 14; ++kt) {
    STAGE_G1(kt + 2, As, Bs);
    COMPUTE_G1(Ac, Bc);
    __builtin_amdgcn_sched_barrier(0);
    asm volatile("s_waitcnt vmcnt(6)" ::: "memory");
    __builtin_amdgcn_s_barrier();
    __builtin_amdgcn_sched_barrier(0);
    char* ta = Ac; Ac = An; An = As; As = ta;
    char* tb = Bc; Bc = Bn; Bn = Bs; Bs = tb;
  }
  COMPUTE_G1(Ac, Bc);
  __builtin_amdgcn_sched_barrier(0);
  asm volatile("s_waitcnt vmcnt(0)" ::: "memory");
  __builtin_amdgcn_s_barrier();
  __builtin_amdgcn_sched_barrier(0);
  COMPUTE_G1(An, Bn);
#undef STAGE_G1
#undef COMPUTE_G1

  __syncthreads();

  u16* lT = (u16*)lds;
#pragma unroll
  for (int sub = 0; sub < 2; ++sub)
#pragma unroll
    for (int bt = 0; bt < 2; ++bt) {
      const int col = cg * 64 + bt * 32 + l31;
#pragma unroll
      for (int r = 0; r < 16; ++r) {
        int row = rb * 64 + sub * 32 + (r & 3) + 8 * (r >> 2) + 4 * lhi;
        lT[row * 136 + col] = f2bf(acc[sub][bt][r]);
      }
    }
  __syncthreads();

#pragma unroll
  for (int i = 0; i < 8; ++i) {
    int G = i * 256 + t;
    int row = G >> 4, gg = G & 15;
    uint4 v = *reinterpret_cast<const uint4*>(&lT[row * 136 + gg * 8]);
    *reinterpret_cast<uint4*>(&hbf[(size_t)(row0 + row) * 512 + col0 + gg * 8]) = v;
  }
  const int bb = row0 >> 10;
  const int nb = row0 & 1023;
  u16* hb2 = hbt2 + (size_t)bb * 524288;
#pragma unroll
  for (int i = 0; i < 8; ++i) {
    int G = i * 256 + t;
    int col = G & 127, rg = G >> 7;
    u32 wd[4];
#pragma unroll
    for (int jj = 0; jj < 4; ++jj) {
      u16 lo = lT[(rg * 8 + 2 * jj) * 136 + col];
      u16 hi = lT[(rg * 8 + 2 * jj + 1) * 136 + col];
      wd[jj] = (u32)lo | ((u32)hi << 16);
    }
    uint4 o = {wd[0], wd[1], wd[2], wd[3]};
    const int m0 = nb + rg * 8;
    const int f = col0 + col;
    size_t idx = (size_t)(m0 >> 4) * 8192 + (size_t)(f >> 5) * 512 + (size_t)((m0 >> 3) & 1) * 256 + (size_t)(f & 31) * 8;
    *reinterpret_cast<uint4*>(&hb2[idx]) = o;
  }
  {
    const int r2 = t >> 1, half = t & 1;
    float d1 = 0.f, d2 = 0.f;
#pragma unroll
    for (int i = 0; i < 8; ++i) {
      uint4 v = *reinterpret_cast<const uint4*>(&lT[r2 * 136 + half * 64 + i * 8]);
      u32 wds[4] = {v.x, v.y, v.z, v.w};
#pragma unroll
      for (int jj = 0; jj < 8; ++jj) {
        float h = bf2f((u16)(wds[jj >> 1] >> ((jj & 1) * 16)));
        d1 += h * a_l[half * 64 + i * 8 + jj];
        d2 += h * a_l[128 + half * 64 + i * 8 + jj];
      }
    }
    d1 += __shfl_xor(d1, 1);
    d2 += __shfl_xor(d2, 1);
    if (half == 0) {
      s1p[cb * 16384 + row0 + r2] = d1;
      s2p[cb * 16384 + row0 + r2] = d2;
    }
  }
}

// ---------- reduce score partials -> s1L, s2L (scaled by log2e) ----------
__global__ __launch_bounds__(256) void k_reduce(const float* __restrict__ s1p, const float* __restrict__ s2p,
                                                float* __restrict__ s1L, float* __restrict__ s2L) {
  int id = blockIdx.x * 256 + threadIdx.x;
  float d1 = s1p[id] + s1p[16384 + id] + s1p[32768 + id] + s1p[49152 + id];
  float d2 = s2p[id] + s2p[16384 + id] + s2p[32768 + id] + s2p[49152 + id];
  s1L[id] = d1 * LOG2E;
  s2L[id] = d2 * LOG2E;
}

// ---------- attn: 32x32x16 MFMA, wave = 64 rows x 128 cols (acc0+acc1).
// Grid 512 x 128 threads (2 waves/block). Halved B traffic; depth-3 reg pipeline. ----------
__global__ __launch_bounds__(128, 1) void k_attn(const u16* __restrict__ hbt2, const u16* __restrict__ hbf,
                                                 const float* __restrict__ s1Lg, const float* __restrict__ s2Lg,
                                                 const float* __restrict__ betag, float* __restrict__ out) {
  __shared__ __attribute__((aligned(16))) float e1_l[1024];
  __shared__ __attribute__((aligned(16))) float e2_l[1024];
  __shared__ __attribute__((aligned(16))) float inv_l[128];
  const int t = threadIdx.x;
  const int lane = t & 63;
  const int w = t >> 6;          // 0..1 : row half of the block's 128 rows
  const int l31 = lane & 31, lhi = lane >> 5;

  const int B = blockIdx.x;
  const int b = (B & 7) * 2 + ((B >> 3) & 1);   // XCD swizzle: 2 batches/XCD L2
  const int j = B >> 4;                          // 0..31 = 8 n-tiles x 4 c-tiles
  const int n0 = (j >> 2) * 128;
  const int c0 = (j & 3) * 128;

  const u16* hb2 = hbt2 + (size_t)b * 524288;

  for (int i = t; i < 1024; i += 128) {
    float v = s2Lg[b * 1024 + i];
    e1_l[i] = exp2f(v);
    e2_l[i] = exp2f(ALPHA * v);
  }

  // two row-groups per wave: rows n0 + w*64 + {0,32} + l31
  const float s1a = s1Lg[b * 1024 + n0 + w * 64 + l31];
  const float s1b = s1Lg[b * 1024 + n0 + w * 64 + 32 + l31];
  const float c1a = exp2f(s1a), c2a = exp2f(ALPHA * s1a);
  const float c1b = exp2f(s1b), c2b = exp2f(ALPHA * s1b);

  f32x16 acc0[4], acc1[4];
#pragma unroll
  for (int ct = 0; ct < 4; ++ct) {
#pragma unroll
    for (int r = 0; r < 16; ++r) { acc0[ct][r] = 0.f; acc1[ct][r] = 0.f; }
  }
  float psum0 = 0.f, psum1 = 0.f;

  __syncthreads();   // tables visible

  const u16* bp = hb2 + (size_t)(c0 >> 5) * 512 + (size_t)(lhi * 32 + l31) * 8;

#define LOAD_B(dst, s)                                                                         \
  {                                                                                            \
    const u16* np_ = bp + (size_t)(s) * 8192;                                                  \
    _Pragma("unroll")                                                                          \
    for (int ct = 0; ct < 4; ++ct) dst[ct] = *reinterpret_cast<const bf16x8*>(np_ + ct * 512); \
  }

#define STEP_ATTN(s, buf)                                                       \
  {                                                                             \
    const int mo = (s) * 16 + lhi * 8;                                          \
    f32x4 ea = *reinterpret_cast<const f32x4*>(&e1_l[mo]);                      \
    f32x4 eb = *reinterpret_cast<const f32x4*>(&e1_l[mo + 4]);                  \
    f32x4 fa = *reinterpret_cast<const f32x4*>(&e2_l[mo]);                      \
    f32x4 fb = *reinterpret_cast<const f32x4*>(&e2_l[mo + 4]);                  \
    bf16x8 af0, af1;                                                            \
    _Pragma("unroll")                                                           \
    for (int q = 0; q < 4; ++q) {                                               \
      float pa0 = fmaxf(c1a * ea[q], c2a * fa[q]);                              \
      float pa1 = fmaxf(c1a * eb[q], c2a * fb[q]);                              \
      float pb0 = fmaxf(c1b * ea[q], c2b * fa[q]);                              \
      float pb1 = fmaxf(c1b * eb[q], c2b * fb[q]);                              \
      psum0 += pa0 + pa1;                                                       \
      psum1 += pb0 + pb1;                                                       \
      af0[q] = (__bf16)pa0; af0[q + 4] = (__bf16)pa1;                           \
      af1[q] = (__bf16)pb0; af1[q + 4] = (__bf16)pb1;                           \
    }                                                                           \
    _Pragma("unroll")                                                           \
    for (int ct = 0; ct < 4; ++ct) {                                            \
      acc0[ct] = __builtin_amdgcn_mfma_f32_32x32x16_bf16(af0, (buf)[ct], acc0[ct], 0, 0, 0); \
      acc1[ct] = __builtin_amdgcn_mfma_f32_32x32x16_bf16(af1, (buf)[ct], acc1[ct], 0, 0, 0); \
    }                                                                           \
  }

  bf16x8 P0[4], P1[4], P2[4];
  LOAD_B(P0, 0);
  LOAD_B(P1, 1);
  LOAD_B(P2, 2);

#pragma unroll 1
  for (int s = 0; s < 63; s += 3) {
    STEP_ATTN(s + 0, P0); LOAD_B(P0, (s + 3) & 63);
    STEP_ATTN(s + 1, P1); LOAD_B(P1, (s + 4) & 63);
    STEP_ATTN(s + 2, P2); LOAD_B(P2, (s + 5) & 63);
  }
  STEP_ATTN(63, P0);
#undef LOAD_B
#undef STEP_ATTN

  // denom: lane pair (l31, l31+32) covers all 1024 m for each row-group row
  psum0 += __shfl_xor(psum0, 32);
  psum1 += __shfl_xor(psum1, 32);
  if (lhi == 0) {
    inv_l[w * 64 + l31] = 1.0f / psum0;
    inv_l[w * 64 + 32 + l31] = 1.0f / psum1;
  }
  __syncthreads();

  const float beta = betag[0];
  const u16* hf = hbf + (size_t)b * 1024 * 512;

#define EPILOGUE(ACC, RG)                                                                 \
  {                                                                                       \
    _Pragma("unroll")                                                                     \
    for (int rg4 = 0; rg4 < 4; ++rg4) {                                                   \
      const int rl = rg4 * 8 + lhi * 4;                                                   \
      const int rowb = n0 + w * 64 + (RG) * 32 + rl;                                      \
      f32x4 iv = *reinterpret_cast<const f32x4*>(&inv_l[w * 64 + (RG) * 32 + rl]);        \
      _Pragma("unroll")                                                                   \
      for (int ct = 0; ct < 4; ++ct) {                                                    \
        const int colv = c0 + ct * 32 + l31;                                              \
        _Pragma("unroll")                                                                 \
        for (int q = 0; q < 4; ++q) {                                                     \
          float hv = bf2f(hf[(size_t)(rowb + q) * 512 + colv]);                           \
          float xv = ACC[ct][rg4 * 4 + q] * iv[q] + beta * hv;                            \
          out[((size_t)b * 1024 + rowb + q) * 512 + colv] = xv > 0.f ? xv : __expf(xv) - 1.0f; \
        }                                                                                 \
      }                                                                                   \
    }                                                                                     \
  }

  EPILOGUE(acc0, 0);
  EPILOGUE(acc1, 1);
#undef EPILOGUE
}

extern "C" void kernel_launch(void* const* d_in, const int* in_sizes, int n_in,
                              void* d_out, int out_size, void* d_ws, size_t ws_size,
                              hipStream_t stream) {
  const float* x = (const float*)d_in[0];
  const float* W = (const float*)d_in[1];
  const float* a = (const float*)d_in[2];
  const float* beta = (const float*)d_in[3];
  float* out = (float*)d_out;

  char* ws = (char*)d_ws;
  u16* hbf = (u16*)ws;                              // 16 MB
  u16* hbt2 = (u16*)(ws + (16u << 20));             // 16 MB, tiled layout
  u16* wbt = (u16*)(ws + (32u << 20));              // 512 KB
  float* s1p = (float*)(ws + (32u << 20) + (512u << 10));   // 256 KB
  float* s2p = (float*)(ws + (32u << 20) + (768u << 10));   // 256 KB
  float* s1L = (float*)(ws + (33u << 20));          // 64 KB
  float* s2L = (float*)(ws + (33u << 20) + (64u << 10));

  k_cast_wT<<<1024, 256, 0, stream>>>(W, wbt);
  k_gemm1<<<512, 256, 0, stream>>>(x, wbt, a, hbf, hbt2, s1p, s2p);
  k_reduce<<<64, 256, 0, stream>>>(s1p, s2p, s1L, s2L);
  k_attn<<<512, 128, 0, stream>>>(hbt2, hbf, s1L, s2L, beta, out);
}